// Round 23
// baseline (181.867 us; speedup 1.0000x reference)
//
#include <hip/hip_runtime.h>
#include <hip/hip_bf16.h>

#define T_SEQ 2048
#define BATCH 4
#define NH    16
#define DM    1024
#define HD    64

typedef __attribute__((ext_vector_type(4))) float  f32x4;
typedef __attribute__((ext_vector_type(8))) short  s16x8;
typedef __attribute__((ext_vector_type(4))) short  s16x4;

__device__ __forceinline__ unsigned short f2b(float f) {
  union { float f; unsigned u; } v; v.f = f;
  unsigned u = v.u;
  unsigned r = 0x7fffu + ((u >> 16) & 1u);
  u += r;
  return (unsigned short)(u >> 16);
}

__device__ __forceinline__ f32x4 mfma16(s16x8 a, s16x8 b, f32x4 c) {
  return __builtin_amdgcn_mfma_f32_16x16x32_bf16(a, b, c, 0, 0, 0);
}

__device__ __forceinline__ float exp2_fast(float x) {
  float r; asm("v_exp_f32 %0, %1" : "=v"(r) : "v"(x)); return r;
}

__device__ __forceinline__ unsigned cvt_pk_bf16(float lo, float hi) {
  unsigned r; asm("v_cvt_pk_bf16_f32 %0, %1, %2" : "=v"(r) : "v"(lo), "v"(hi)); return r;
}

#define BAR() __builtin_amdgcn_s_barrier()
#define SCB() __builtin_amdgcn_sched_barrier(0)
#define LGK(n) do { asm volatile("s_waitcnt lgkmcnt(" #n ")" ::: "memory"); SCB(); } while (0)
#define VMC(n) do { asm volatile("s_waitcnt vmcnt(" #n ")" ::: "memory"); } while (0)

// ---- fused fp32 -> bf16 convert; Q-rows of w_qkv pre-scaled by 0.125*log2(e) ----
__global__ void cvt_all(const float* __restrict__ x, const float* __restrict__ wq,
                        const float* __restrict__ wo,
                        unsigned short* __restrict__ xb, unsigned short* __restrict__ wqb,
                        unsigned short* __restrict__ wob) {
  const int N4X = (BATCH * T_SEQ * DM) / 4;
  const int N4Q = (3 * DM * DM) / 4;
  const int N4O = (DM * DM) / 4;
  const int N4QSCALED = (DM * DM) / 4;
  int i = blockIdx.x * blockDim.x + threadIdx.x;
  int stride = gridDim.x * blockDim.x;
  for (int j = i; j < N4X + N4Q + N4O; j += stride) {
    const float* src; unsigned short* dst; int k; float scale = 1.f;
    if (j < N4X) { src = x; dst = xb; k = j; }
    else if (j < N4X + N4Q) {
      k = j - N4X; src = wq; dst = wqb;
      if (k < N4QSCALED) scale = 0.18033688011112042f;   // (1/8)*log2(e)
    } else { k = j - N4X - N4Q; src = wo; dst = wob; }
    f32x4 v = ((const f32x4*)src)[k];
    s16x4 o;
    o.x = (short)f2b(v.x * scale); o.y = (short)f2b(v.y * scale);
    o.z = (short)f2b(v.z * scale); o.w = (short)f2b(v.w * scale);
    ((s16x4*)dst)[k] = o;
  }
}

// ======= 256xBN 8-phase GEMM, depth-4-phase prefetch: C = A[M,K]*B[N,K]^T ======
template<int NB>
__device__ __forceinline__ void rdN(s16x8 (&d)[4], const char* base, int rbase, int cb) {
#pragma unroll
  for (int j = 0; j < NB; ++j)
    d[j] = *(const s16x8*)(base + (rbase + j * 16) * 128 + cb);
}

__device__ __forceinline__ void stage_half(const unsigned short* __restrict__ Msrc,
                                           int rt0, int kt, char* lbase, int half,
                                           int srow8, int c2src, int c2lin, int Kd) {
#pragma unroll
  for (int q = 0; q < 2; ++q) {
    int rl = half * 128 + q * 64 + srow8;
    const char* src = (const char*)(Msrc + (size_t)(rt0 + rl) * Kd + kt) + c2src;
    __builtin_amdgcn_global_load_lds((const void*)src, (void*)(lbase + rl * 128 + c2lin),
                                     16, 0, 0);
  }
}

template<int NB>
__device__ __forceinline__ void clust(f32x4 (&acc)[8][4], const s16x8 (&a)[4],
                                      const s16x8 (&b)[4], int mb) {
  __builtin_amdgcn_s_setprio(1);
#pragma unroll
  for (int j = 0; j < 4; ++j)
#pragma unroll
    for (int n = 0; n < NB; ++n)
      acc[mb + j][n] = mfma16(a[j], b[n], acc[mb + j][n]);
  __builtin_amdgcn_s_setprio(0);
}

// BN128==0: 256x256 tile (B frags NB=4). BN128==1: 256x128 tile (NB=2, B single-half).
template<int OUTF32, int BN128>
__global__ __launch_bounds__(512, 2)
void gemm8p(const unsigned short* __restrict__ A, const unsigned short* __restrict__ B,
            void* __restrict__ C, int M, int N, int K) {
  constexpr int NB = BN128 ? 2 : 4;
  __shared__ char smem[131072];
  char* A0b = smem;
  char* A1b = smem + 32768;
  char* B0b = smem + 65536;
  char* B1b = smem + 98304;

  const int tid = threadIdx.x;
  const int lane = tid & 63;
  const int w = tid >> 6;
  const int wm = w >> 2, wn = w & 3;
  const int lr = lane & 15, g = lane >> 4;

  // XCD-aware bijective swizzle (grid total % 8 == 0)
  const int gx = gridDim.x, nwg = gx * gridDim.y;
  const int bid = blockIdx.y * gx + blockIdx.x;
  const int cpx = nwg >> 3;
  const int b2 = (bid & 7) * cpx + (bid >> 3);
  const int row0 = (b2 % gx) * 256;
  const int col0 = (b2 / gx) * (BN128 ? 128 : 256);

  // staging: linear LDS dest, source col permuted; involution slot^(row&7)
  const int srow8 = tid >> 3;
  const int c2lin = (tid & 7) * 16;
  const int c2src = ((tid & 7) ^ (srow8 & 7)) * 16;

  const int swz = (lr & 7) << 4;
  const int cs0 = (g * 16) ^ swz;
  const int cs1 = (64 + g * 16) ^ swz;
  const int rAlo = wm * 128 + lr;
  const int rAhi = rAlo + 64;
  const int rB = wn * (NB * 16) + lr;

  f32x4 acc[8][4] = {};
  s16x8 aP[4], aQ[4], aR[4], bP[4], bQ[4];

  const int NT = K / 64;

  stage_half(A, row0, 0, A0b, 0, srow8, c2src, c2lin, K);
  stage_half(A, row0, 0, A0b, 1, srow8, c2src, c2lin, K);
  stage_half(B, col0, 0, B0b, 0, srow8, c2src, c2lin, K);
  if constexpr (!BN128) stage_half(B, col0, 0, B0b, 1, srow8, c2src, c2lin, K);
  stage_half(A, row0, 64, A1b, 0, srow8, c2src, c2lin, K);
  VMC(2);
  BAR();
  rdN<4>(aP, A0b, rAlo, cs0);
  rdN<NB>(bP, B0b, rB, cs0);

  auto body = [&](char* Ac, char* Bc, char* An, char* Bn, int t) {
    const int ktn  = min(t + 1, NT - 1) * 64;
    const int ktn2 = min(t + 2, NT - 1) * 64;
    // ph0
    rdN<4>(aQ, Ac, rAhi, cs0);
    stage_half(A, row0, ktn, An, 1, srow8, c2src, c2lin, K);
    BAR(); LGK(4);
    clust<NB>(acc, aP, bP, 0);
    BAR();
    // ph1
    rdN<4>(aP, Ac, rAlo, cs1);
    rdN<4>(aR, Ac, rAhi, cs1);
    rdN<NB>(bQ, Bc, rB, cs1);
    stage_half(B, col0, ktn, Bn, 0, srow8, c2src, c2lin, K);
    BAR();
    if constexpr (BN128) { LGK(10); } else { LGK(12); }
    clust<NB>(acc, aQ, bP, 4);
    BAR();
    // ph2
    if constexpr (!BN128) stage_half(B, col0, ktn, Bn, 1, srow8, c2src, c2lin, K);
    BAR(); LGK(0);
    clust<NB>(acc, aP, bQ, 0);
    BAR();
    // ph3 (K-tile boundary)
    stage_half(A, row0, ktn2, Ac, 0, srow8, c2src, c2lin, K);
    VMC(2);
    BAR();
    rdN<4>(aP, An, rAlo, cs0);
    rdN<NB>(bP, Bn, rB, cs0);
    clust<NB>(acc, aR, bQ, 4);
    BAR();
  };

#pragma unroll 1
  for (int tt = 0; tt < NT; tt += 2) {
    body(A0b, B0b, A1b, B1b, tt);
    body(A1b, B1b, A0b, B0b, tt + 1);
  }

#pragma unroll
  for (int m = 0; m < 8; ++m)
#pragma unroll
    for (int n = 0; n < NB; ++n)
#pragma unroll
      for (int i = 0; i < 4; ++i) {
        int row = row0 + wm * 128 + m * 16 + g * 4 + i;
        int col = col0 + wn * (NB * 16) + n * 16 + lr;
        if (OUTF32)
          ((float*)C)[(size_t)row * N + col] = acc[m][n][i];
        else
          ((unsigned short*)C)[(size_t)row * N + col] = f2b(acc[m][n][i]);
      }
}

// ---- causal flash attention: single-buffered Vt (44032 B) + single-qt 1024-block grid ----
// grid (64 bh, 16 qt-slots); qt = 15 - blockIdx.y (heavy-first LPT). De-confounded occupancy
// test: grid supplies 4 blocks/CU; LDS 44 KB permits 3 resident.
__global__ __launch_bounds__(512)
void attn_kernel(const unsigned short* __restrict__ qkv,
                 unsigned short* __restrict__ out) {
  __shared__ unsigned short Ks[2][64 * 64];   // 16 KiB
  __shared__ unsigned short Vt[64 * 72];      // 9 KiB (single buffer)
  __shared__ unsigned short Ps[8][16 * 72];   // 18 KiB

  const int tid  = threadIdx.x;
  const int lane = tid & 63;
  const int w    = tid >> 6;
  const int lr   = lane & 15, g = lane >> 4;
  const int bh   = blockIdx.x;
  const int qt   = 15 - (int)blockIdx.y;   // heavy-first
  const int b    = bh >> 4, h = bh & 15;
  const size_t rb = (size_t)b * T_SEQ;

  const bool grpV = (tid < 256);
  const int vd0 = (tid & 7) * 8, vr0 = (tid >> 3) * 2;
  const int t2  = tid - 256;
  const int kr0 = t2 >> 3, kc0 = t2 & 7;

  const int q0 = qt * 128;
  const int qr = q0 + w * 16;
  const int qq = qr + lr;
  const int nt = 2 * qt + 2;
  const int qmax = qr + 15;

  s16x8 qf[2];
  {
    const unsigned short* qp = qkv + (rb + qq) * 3072 + h * 64;
    qf[0] = *(const s16x8*)(qp + g * 8);
    qf[1] = *(const s16x8*)(qp + 32 + g * 8);
  }

  float mI = -1e30f, lI = 0.f;
  f32x4 o[4] = {};

  s16x8 pre0, pre1;
  {
    if (grpV) {
      const unsigned short* vp = &qkv[(rb + vr0) * 3072 + 2048 + h * 64 + vd0];
      pre0 = *(const s16x8*)vp;
      pre1 = *(const s16x8*)(vp + 3072);
    } else {
      const unsigned short* kp = &qkv[(rb + kr0) * 3072 + 1024 + h * 64 + kc0 * 8];
      pre0 = *(const s16x8*)kp;
      pre1 = *(const s16x8*)(kp + 32 * 3072);
    }
  }

  for (int t = 0; t < nt; ++t) {
    const int cur = t & 1;
    // ---- commit tile t regs -> LDS ----
    if (grpV) {
#pragma unroll
      for (int jj = 0; jj < 8; ++jj) {
        int d = vd0 + jj;
        int sw = ((d >> 3) & 7) << 4;   // row-group swizzle (conflict-free read)
        unsigned val = (unsigned)(unsigned short)pre0[jj] |
                       ((unsigned)(unsigned short)pre1[jj] << 16);
        *(unsigned*)((char*)&Vt[0] + d * 144 + ((vr0 * 2) ^ sw)) = val;
      }
    } else {
      *(s16x8*)((char*)&Ks[cur][0] + kr0 * 128 + ((kc0 * 16) ^ ((kr0 & 7) << 4))) = pre0;
      int kr1 = kr0 + 32;
      *(s16x8*)((char*)&Ks[cur][0] + kr1 * 128 + ((kc0 * 16) ^ ((kr1 & 7) << 4))) = pre1;
    }
    __syncthreads();

    // ---- issue tile t+1 loads (in flight during compute) ----
    if (t + 1 < nt) {
      const int kv0n = (t + 1) * 64;
      if (grpV) {
        const unsigned short* vp = &qkv[(rb + kv0n + vr0) * 3072 + 2048 + h * 64 + vd0];
        pre0 = *(const s16x8*)vp;
        pre1 = *(const s16x8*)(vp + 3072);
      } else {
        const unsigned short* kp = &qkv[(rb + kv0n + kr0) * 3072 + 1024 + h * 64 + kc0 * 8];
        pre0 = *(const s16x8*)kp;
        pre1 = *(const s16x8*)(kp + 32 * 3072);
      }
    }

    const int kv0 = t * 64;
    if (kv0 <= qmax) {
      f32x4 s4[4];
      __builtin_amdgcn_s_setprio(1);
#pragma unroll
      for (int kc = 0; kc < 4; ++kc) {
        int row = kc * 16 + lr;
        const char* kbase = (const char*)&Ks[cur][0] + row * 128;
        int sw = (row & 7) << 4;
        s16x8 kf0 = *(const s16x8*)(kbase + ((g * 16) ^ sw));
        s16x8 kf1 = *(const s16x8*)(kbase + ((64 + g * 16) ^ sw));
        f32x4 s = {};
        s = mfma16(kf0, qf[0], s);
        s = mfma16(kf1, qf[1], s);
        s4[kc] = s;
      }
      __builtin_amdgcn_s_setprio(0);

      if (kv0 + 63 > qr) {
#pragma unroll
        for (int kc = 0; kc < 4; ++kc)
#pragma unroll
          for (int i = 0; i < 4; ++i) {
            int key = kv0 + kc * 16 + g * 4 + i;
            if (key > qq) s4[kc][i] = -1e30f;
          }
      }

      float mx = fmaxf(fmaxf(fmaxf(s4[0][0], s4[0][1]), fmaxf(s4[0][2], s4[0][3])),
                 fmaxf(fmaxf(fmaxf(s4[1][0], s4[1][1]), fmaxf(s4[1][2], s4[1][3])),
                 fmaxf(fmaxf(fmaxf(s4[2][0], s4[2][1]), fmaxf(s4[2][2], s4[2][3])),
                       fmaxf(fmaxf(s4[3][0], s4[3][1]), fmaxf(s4[3][2], s4[3][3])))));
      mx = fmaxf(mx, __shfl_xor(mx, 16));
      mx = fmaxf(mx, __shfl_xor(mx, 32));

      const bool defer = __all(mx - mI <= 11.5f);
      float alpha;
      if (defer) {
        alpha = 1.f;
      } else {
        float mn = fmaxf(mI, mx);
        alpha = exp2_fast(mI - mn);
        mI = mn;
      }
      float rs = 0.f;
#pragma unroll
      for (int kc = 0; kc < 4; ++kc)
#pragma unroll
        for (int i = 0; i < 4; ++i) {
          float p = exp2_fast(s4[kc][i] - mI);
          s4[kc][i] = p;
          rs += p;
        }
      rs += __shfl_xor(rs, 16);
      rs += __shfl_xor(rs, 32);
      lI = lI * alpha + rs;

      {
        char* pw = (char*)&Ps[w][0] + lr * 144;
#pragma unroll
        for (int kc = 0; kc < 4; ++kc) {
          unsigned v0 = cvt_pk_bf16(s4[kc][0], s4[kc][1]);
          unsigned v1 = cvt_pk_bf16(s4[kc][2], s4[kc][3]);
          unsigned long long pv = (unsigned long long)v0 | ((unsigned long long)v1 << 32);
          *(unsigned long long*)(pw + kc * 32 + g * 8) = pv;
        }
      }

      if (!defer) {
#pragma unroll
        for (int n = 0; n < 4; ++n)
#pragma unroll
          for (int i = 0; i < 4; ++i)
            o[n][i] *= alpha;
      }

      asm volatile("s_waitcnt lgkmcnt(0)" ::: "memory");

      __builtin_amdgcn_s_setprio(1);
#pragma unroll
      for (int kk = 0; kk < 2; ++kk) {
        s16x8 pf = *(const s16x8*)((const char*)&Ps[w][0] + lr * 144 + kk * 64 + g * 16);
#pragma unroll
        for (int n = 0; n < 4; ++n) {
          int d = n * 16 + lr;
          int sw = ((d >> 3) & 7) << 4;   // must match V-write swizzle
          s16x8 vf = *(const s16x8*)((const char*)&Vt[0] + d * 144 + ((kk * 64 + g * 16) ^ sw));
          o[n] = mfma16(vf, pf, o[n]);
        }
      }
      __builtin_amdgcn_s_setprio(0);
    }
    // ---- end-of-tile barrier: all PV reads of Vt retired before next commit ----
    __syncthreads();
  }

  float rl = 1.f / lI;
#pragma unroll
  for (int n = 0; n < 4; ++n) {
    unsigned p0 = cvt_pk_bf16(o[n][0] * rl, o[n][1] * rl);
    unsigned p1 = cvt_pk_bf16(o[n][2] * rl, o[n][3] * rl);
    unsigned long long pv = (unsigned long long)p0 | ((unsigned long long)p1 << 32);
    *(unsigned long long*)&out[(rb + qq) * 1024 + h * 64 + n * 16 + g * 4] = pv;
  }
}

// ---------------- launcher ----------------
extern "C" void kernel_launch(void* const* d_in, const int* in_sizes, int n_in,
                              void* d_out, int out_size, void* d_ws, size_t ws_size,
                              hipStream_t stream) {
  const float* x     = (const float*)d_in[0];
  const float* w_qkv = (const float*)d_in[1];
  const float* w_out = (const float*)d_in[2];

  const size_t n_x   = (size_t)BATCH * T_SEQ * DM;
  const size_t n_wq  = (size_t)3 * DM * DM;
  const size_t n_wo  = (size_t)DM * DM;
  const size_t n_qkv = (size_t)BATCH * T_SEQ * 3 * DM;
  const size_t need  = (n_x + n_wq + n_wo + n_qkv + n_x) * 2;
  if (ws_size < need) return;

  unsigned short* xb  = (unsigned short*)d_ws;
  unsigned short* wqb = xb + n_x;
  unsigned short* wob = wqb + n_wq;
  unsigned short* qkv = wob + n_wo;
  unsigned short* att = qkv + n_qkv;

  cvt_all<<<2048, 256, 0, stream>>>(x, w_qkv, w_out, xb, wqb, wob);

  gemm8p<0, 0><<<dim3(32, 12), 512, 0, stream>>>(xb, wqb, qkv, BATCH * T_SEQ, 3 * DM, DM);
  attn_kernel<<<dim3(64, 16), 512, 0, stream>>>(qkv, att);
  gemm8p<1, 1><<<dim3(32, 8), 512, 0, stream>>>(att, wob, d_out, BATCH * T_SEQ, DM, DM);
}

// Round 24
// 176.900 us; speedup vs baseline: 1.0281x; 1.0281x over previous
//
#include <hip/hip_runtime.h>
#include <hip/hip_bf16.h>

#define T_SEQ 2048
#define BATCH 4
#define NH    16
#define DM    1024
#define HD    64

typedef __attribute__((ext_vector_type(4))) float  f32x4;
typedef __attribute__((ext_vector_type(8))) short  s16x8;
typedef __attribute__((ext_vector_type(4))) short  s16x4;

__device__ __forceinline__ unsigned short f2b(float f) {
  union { float f; unsigned u; } v; v.f = f;
  unsigned u = v.u;
  unsigned r = 0x7fffu + ((u >> 16) & 1u);
  u += r;
  return (unsigned short)(u >> 16);
}

__device__ __forceinline__ f32x4 mfma16(s16x8 a, s16x8 b, f32x4 c) {
  return __builtin_amdgcn_mfma_f32_16x16x32_bf16(a, b, c, 0, 0, 0);
}

__device__ __forceinline__ float exp2_fast(float x) {
  float r; asm("v_exp_f32 %0, %1" : "=v"(r) : "v"(x)); return r;
}

__device__ __forceinline__ unsigned cvt_pk_bf16(float lo, float hi) {
  unsigned r; asm("v_cvt_pk_bf16_f32 %0, %1, %2" : "=v"(r) : "v"(lo), "v"(hi)); return r;
}

#define BAR() __builtin_amdgcn_s_barrier()
#define SCB() __builtin_amdgcn_sched_barrier(0)
#define LGK(n) do { asm volatile("s_waitcnt lgkmcnt(" #n ")" ::: "memory"); SCB(); } while (0)
#define VMC(n) do { asm volatile("s_waitcnt vmcnt(" #n ")" ::: "memory"); } while (0)

// ---- fused fp32 -> bf16 convert; Q-rows of w_qkv pre-scaled by 0.125*log2(e) ----
__global__ void cvt_all(const float* __restrict__ x, const float* __restrict__ wq,
                        const float* __restrict__ wo,
                        unsigned short* __restrict__ xb, unsigned short* __restrict__ wqb,
                        unsigned short* __restrict__ wob) {
  const int N4X = (BATCH * T_SEQ * DM) / 4;
  const int N4Q = (3 * DM * DM) / 4;
  const int N4O = (DM * DM) / 4;
  const int N4QSCALED = (DM * DM) / 4;
  int i = blockIdx.x * blockDim.x + threadIdx.x;
  int stride = gridDim.x * blockDim.x;
  for (int j = i; j < N4X + N4Q + N4O; j += stride) {
    const float* src; unsigned short* dst; int k; float scale = 1.f;
    if (j < N4X) { src = x; dst = xb; k = j; }
    else if (j < N4X + N4Q) {
      k = j - N4X; src = wq; dst = wqb;
      if (k < N4QSCALED) scale = 0.18033688011112042f;   // (1/8)*log2(e)
    } else { k = j - N4X - N4Q; src = wo; dst = wob; }
    f32x4 v = ((const f32x4*)src)[k];
    s16x4 o;
    o.x = (short)f2b(v.x * scale); o.y = (short)f2b(v.y * scale);
    o.z = (short)f2b(v.z * scale); o.w = (short)f2b(v.w * scale);
    ((s16x4*)dst)[k] = o;
  }
}

// ======= 256xBN 8-phase GEMM, depth-4-phase prefetch: C = A[M,K]*B[N,K]^T ======
template<int NB>
__device__ __forceinline__ void rdN(s16x8 (&d)[4], const char* base, int rbase, int cb) {
#pragma unroll
  for (int j = 0; j < NB; ++j)
    d[j] = *(const s16x8*)(base + (rbase + j * 16) * 128 + cb);
}

__device__ __forceinline__ void stage_half(const unsigned short* __restrict__ Msrc,
                                           int rt0, int kt, char* lbase, int half,
                                           int srow8, int c2src, int c2lin, int Kd) {
#pragma unroll
  for (int q = 0; q < 2; ++q) {
    int rl = half * 128 + q * 64 + srow8;
    const char* src = (const char*)(Msrc + (size_t)(rt0 + rl) * Kd + kt) + c2src;
    __builtin_amdgcn_global_load_lds((const void*)src, (void*)(lbase + rl * 128 + c2lin),
                                     16, 0, 0);
  }
}

template<int NB>
__device__ __forceinline__ void clust(f32x4 (&acc)[8][4], const s16x8 (&a)[4],
                                      const s16x8 (&b)[4], int mb) {
  __builtin_amdgcn_s_setprio(1);
#pragma unroll
  for (int j = 0; j < 4; ++j)
#pragma unroll
    for (int n = 0; n < NB; ++n)
      acc[mb + j][n] = mfma16(a[j], b[n], acc[mb + j][n]);
  __builtin_amdgcn_s_setprio(0);
}

// BN128==0: 256x256 tile (B frags NB=4). BN128==1: 256x128 tile (NB=2, B single-half).
template<int OUTF32, int BN128>
__global__ __launch_bounds__(512, 2)
void gemm8p(const unsigned short* __restrict__ A, const unsigned short* __restrict__ B,
            void* __restrict__ C, int M, int N, int K) {
  constexpr int NB = BN128 ? 2 : 4;
  __shared__ char smem[131072];
  char* A0b = smem;
  char* A1b = smem + 32768;
  char* B0b = smem + 65536;
  char* B1b = smem + 98304;

  const int tid = threadIdx.x;
  const int lane = tid & 63;
  const int w = tid >> 6;
  const int wm = w >> 2, wn = w & 3;
  const int lr = lane & 15, g = lane >> 4;

  // XCD-aware bijective swizzle (grid total % 8 == 0)
  const int gx = gridDim.x, nwg = gx * gridDim.y;
  const int bid = blockIdx.y * gx + blockIdx.x;
  const int cpx = nwg >> 3;
  const int b2 = (bid & 7) * cpx + (bid >> 3);
  const int row0 = (b2 % gx) * 256;
  const int col0 = (b2 / gx) * (BN128 ? 128 : 256);

  // staging: linear LDS dest, source col permuted; involution slot^(row&7)
  const int srow8 = tid >> 3;
  const int c2lin = (tid & 7) * 16;
  const int c2src = ((tid & 7) ^ (srow8 & 7)) * 16;

  const int swz = (lr & 7) << 4;
  const int cs0 = (g * 16) ^ swz;
  const int cs1 = (64 + g * 16) ^ swz;
  const int rAlo = wm * 128 + lr;
  const int rAhi = rAlo + 64;
  const int rB = wn * (NB * 16) + lr;

  f32x4 acc[8][4] = {};
  s16x8 aP[4], aQ[4], aR[4], bP[4], bQ[4];

  const int NT = K / 64;

  stage_half(A, row0, 0, A0b, 0, srow8, c2src, c2lin, K);
  stage_half(A, row0, 0, A0b, 1, srow8, c2src, c2lin, K);
  stage_half(B, col0, 0, B0b, 0, srow8, c2src, c2lin, K);
  if constexpr (!BN128) stage_half(B, col0, 0, B0b, 1, srow8, c2src, c2lin, K);
  stage_half(A, row0, 64, A1b, 0, srow8, c2src, c2lin, K);
  VMC(2);
  BAR();
  rdN<4>(aP, A0b, rAlo, cs0);
  rdN<NB>(bP, B0b, rB, cs0);

  auto body = [&](char* Ac, char* Bc, char* An, char* Bn, int t) {
    const int ktn  = min(t + 1, NT - 1) * 64;
    const int ktn2 = min(t + 2, NT - 1) * 64;
    // ph0
    rdN<4>(aQ, Ac, rAhi, cs0);
    stage_half(A, row0, ktn, An, 1, srow8, c2src, c2lin, K);
    BAR(); LGK(4);
    clust<NB>(acc, aP, bP, 0);
    BAR();
    // ph1
    rdN<4>(aP, Ac, rAlo, cs1);
    rdN<4>(aR, Ac, rAhi, cs1);
    rdN<NB>(bQ, Bc, rB, cs1);
    stage_half(B, col0, ktn, Bn, 0, srow8, c2src, c2lin, K);
    BAR();
    if constexpr (BN128) { LGK(10); } else { LGK(12); }
    clust<NB>(acc, aQ, bP, 4);
    BAR();
    // ph2
    if constexpr (!BN128) stage_half(B, col0, ktn, Bn, 1, srow8, c2src, c2lin, K);
    BAR(); LGK(0);
    clust<NB>(acc, aP, bQ, 0);
    BAR();
    // ph3 (K-tile boundary)
    stage_half(A, row0, ktn2, Ac, 0, srow8, c2src, c2lin, K);
    VMC(2);
    BAR();
    rdN<4>(aP, An, rAlo, cs0);
    rdN<NB>(bP, Bn, rB, cs0);
    clust<NB>(acc, aR, bQ, 4);
    BAR();
  };

#pragma unroll 1
  for (int tt = 0; tt < NT; tt += 2) {
    body(A0b, B0b, A1b, B1b, tt);
    body(A1b, B1b, A0b, B0b, tt + 1);
  }

#pragma unroll
  for (int m = 0; m < 8; ++m)
#pragma unroll
    for (int n = 0; n < NB; ++n)
#pragma unroll
      for (int i = 0; i < 4; ++i) {
        int row = row0 + wm * 128 + m * 16 + g * 4 + i;
        int col = col0 + wn * (NB * 16) + n * 16 + lr;
        if (OUTF32)
          ((float*)C)[(size_t)row * N + col] = acc[m][n][i];
        else
          ((unsigned short*)C)[(size_t)row * N + col] = f2b(acc[m][n][i]);
      }
}

// ---------------- causal flash attention (R14 best: paired q-tiles + V-read swizzle) ----------------
// grid: 512 blocks; block processes q-tiles {pi, 15-pi} -> uniform 34 tile-iters/block
__global__ __launch_bounds__(512)
void attn_kernel(const unsigned short* __restrict__ qkv,
                 unsigned short* __restrict__ out) {
  __shared__ unsigned short Ks[2][64 * 64];
  __shared__ unsigned short Vt[2][64 * 72];
  __shared__ unsigned short Ps[8][16 * 72];

  const int tid  = threadIdx.x;
  const int lane = tid & 63;
  const int w    = tid >> 6;
  const int lr   = lane & 15, g = lane >> 4;
  const int bid  = blockIdx.x;
  const int bh   = bid & 63;
  const int pi   = bid >> 6;
  const int b    = bh >> 4, h = bh & 15;
  const size_t rb = (size_t)b * T_SEQ;

  const bool grpV = (tid < 256);
  const int vd0 = (tid & 7) * 8, vr0 = (tid >> 3) * 2;
  const int t2  = tid - 256;
  const int kr0 = t2 >> 3, kc0 = t2 & 7;

#pragma unroll 1
  for (int ph = 0; ph < 2; ++ph) {
    const int qt = ph ? (15 - pi) : pi;
    const int q0 = qt * 128;
    const int qr = q0 + w * 16;
    const int qq = qr + lr;
    const int nt = 2 * qt + 2;
    const int qmax = qr + 15;

    s16x8 qf[2];
    {
      const unsigned short* qp = qkv + (rb + qq) * 3072 + h * 64;
      qf[0] = *(const s16x8*)(qp + g * 8);
      qf[1] = *(const s16x8*)(qp + 32 + g * 8);
    }

    float mI = -1e30f, lI = 0.f;
    f32x4 o[4] = {};

    s16x8 pre0, pre1;
    {
      if (grpV) {
        const unsigned short* vp = &qkv[(rb + vr0) * 3072 + 2048 + h * 64 + vd0];
        pre0 = *(const s16x8*)vp;
        pre1 = *(const s16x8*)(vp + 3072);
      } else {
        const unsigned short* kp = &qkv[(rb + kr0) * 3072 + 1024 + h * 64 + kc0 * 8];
        pre0 = *(const s16x8*)kp;
        pre1 = *(const s16x8*)(kp + 32 * 3072);
      }
    }

    for (int t = 0; t < nt; ++t) {
      const int cur = t & 1;
      if (grpV) {
#pragma unroll
        for (int jj = 0; jj < 8; ++jj) {
          int d = vd0 + jj;
          int sw = ((d >> 3) & 7) << 4;   // row-group swizzle (conflict-free read)
          unsigned val = (unsigned)(unsigned short)pre0[jj] |
                         ((unsigned)(unsigned short)pre1[jj] << 16);
          *(unsigned*)((char*)&Vt[cur][0] + d * 144 + ((vr0 * 2) ^ sw)) = val;
        }
      } else {
        *(s16x8*)((char*)&Ks[cur][0] + kr0 * 128 + ((kc0 * 16) ^ ((kr0 & 7) << 4))) = pre0;
        int kr1 = kr0 + 32;
        *(s16x8*)((char*)&Ks[cur][0] + kr1 * 128 + ((kc0 * 16) ^ ((kr1 & 7) << 4))) = pre1;
      }
      __syncthreads();

      if (t + 1 < nt) {
        const int kv0n = (t + 1) * 64;
        if (grpV) {
          const unsigned short* vp = &qkv[(rb + kv0n + vr0) * 3072 + 2048 + h * 64 + vd0];
          pre0 = *(const s16x8*)vp;
          pre1 = *(const s16x8*)(vp + 3072);
        } else {
          const unsigned short* kp = &qkv[(rb + kv0n + kr0) * 3072 + 1024 + h * 64 + kc0 * 8];
          pre0 = *(const s16x8*)kp;
          pre1 = *(const s16x8*)(kp + 32 * 3072);
        }
      }

      const int kv0 = t * 64;
      if (kv0 <= qmax) {
        f32x4 s4[4];
        __builtin_amdgcn_s_setprio(1);
#pragma unroll
        for (int kc = 0; kc < 4; ++kc) {
          int row = kc * 16 + lr;
          const char* kbase = (const char*)&Ks[cur][0] + row * 128;
          int sw = (row & 7) << 4;
          s16x8 kf0 = *(const s16x8*)(kbase + ((g * 16) ^ sw));
          s16x8 kf1 = *(const s16x8*)(kbase + ((64 + g * 16) ^ sw));
          f32x4 s = {};
          s = mfma16(kf0, qf[0], s);
          s = mfma16(kf1, qf[1], s);
          s4[kc] = s;
        }
        __builtin_amdgcn_s_setprio(0);

        if (kv0 + 63 > qr) {
#pragma unroll
          for (int kc = 0; kc < 4; ++kc)
#pragma unroll
            for (int i = 0; i < 4; ++i) {
              int key = kv0 + kc * 16 + g * 4 + i;
              if (key > qq) s4[kc][i] = -1e30f;
            }
        }

        float mx = fmaxf(fmaxf(fmaxf(s4[0][0], s4[0][1]), fmaxf(s4[0][2], s4[0][3])),
                   fmaxf(fmaxf(fmaxf(s4[1][0], s4[1][1]), fmaxf(s4[1][2], s4[1][3])),
                   fmaxf(fmaxf(fmaxf(s4[2][0], s4[2][1]), fmaxf(s4[2][2], s4[2][3])),
                         fmaxf(fmaxf(s4[3][0], s4[3][1]), fmaxf(s4[3][2], s4[3][3])))));
        mx = fmaxf(mx, __shfl_xor(mx, 16));
        mx = fmaxf(mx, __shfl_xor(mx, 32));

        const bool defer = __all(mx - mI <= 11.5f);
        float alpha;
        if (defer) {
          alpha = 1.f;
        } else {
          float mn = fmaxf(mI, mx);
          alpha = exp2_fast(mI - mn);
          mI = mn;
        }
        float rs = 0.f;
#pragma unroll
        for (int kc = 0; kc < 4; ++kc)
#pragma unroll
          for (int i = 0; i < 4; ++i) {
            float p = exp2_fast(s4[kc][i] - mI);
            s4[kc][i] = p;
            rs += p;
          }
        rs += __shfl_xor(rs, 16);
        rs += __shfl_xor(rs, 32);
        lI = lI * alpha + rs;

        {
          char* pw = (char*)&Ps[w][0] + lr * 144;
#pragma unroll
          for (int kc = 0; kc < 4; ++kc) {
            unsigned v0 = cvt_pk_bf16(s4[kc][0], s4[kc][1]);
            unsigned v1 = cvt_pk_bf16(s4[kc][2], s4[kc][3]);
            unsigned long long pv = (unsigned long long)v0 | ((unsigned long long)v1 << 32);
            *(unsigned long long*)(pw + kc * 32 + g * 8) = pv;
          }
        }

        if (!defer) {
#pragma unroll
          for (int n = 0; n < 4; ++n)
#pragma unroll
            for (int i = 0; i < 4; ++i)
              o[n][i] *= alpha;
        }

        asm volatile("s_waitcnt lgkmcnt(0)" ::: "memory");

        __builtin_amdgcn_s_setprio(1);
#pragma unroll
        for (int kk = 0; kk < 2; ++kk) {
          s16x8 pf = *(const s16x8*)((const char*)&Ps[w][0] + lr * 144 + kk * 64 + g * 16);
#pragma unroll
          for (int n = 0; n < 4; ++n) {
            int d = n * 16 + lr;
            int sw = ((d >> 3) & 7) << 4;   // must match V-write swizzle
            s16x8 vf = *(const s16x8*)((const char*)&Vt[cur][0] + d * 144 + ((kk * 64 + g * 16) ^ sw));
            o[n] = mfma16(vf, pf, o[n]);
          }
        }
        __builtin_amdgcn_s_setprio(0);
      }
    }

    float rl = 1.f / lI;
#pragma unroll
    for (int n = 0; n < 4; ++n) {
      unsigned p0 = cvt_pk_bf16(o[n][0] * rl, o[n][1] * rl);
      unsigned p1 = cvt_pk_bf16(o[n][2] * rl, o[n][3] * rl);
      unsigned long long pv = (unsigned long long)p0 | ((unsigned long long)p1 << 32);
      *(unsigned long long*)&out[(rb + qq) * 1024 + h * 64 + n * 16 + g * 4] = pv;
    }
  }
}

// ---------------- launcher ----------------
extern "C" void kernel_launch(void* const* d_in, const int* in_sizes, int n_in,
                              void* d_out, int out_size, void* d_ws, size_t ws_size,
                              hipStream_t stream) {
  const float* x     = (const float*)d_in[0];
  const float* w_qkv = (const float*)d_in[1];
  const float* w_out = (const float*)d_in[2];

  const size_t n_x   = (size_t)BATCH * T_SEQ * DM;
  const size_t n_wq  = (size_t)3 * DM * DM;
  const size_t n_wo  = (size_t)DM * DM;
  const size_t n_qkv = (size_t)BATCH * T_SEQ * 3 * DM;
  const size_t need  = (n_x + n_wq + n_wo + n_qkv + n_x) * 2;
  if (ws_size < need) return;

  unsigned short* xb  = (unsigned short*)d_ws;
  unsigned short* wqb = xb + n_x;
  unsigned short* wob = wqb + n_wq;
  unsigned short* qkv = wob + n_wo;
  unsigned short* att = qkv + n_qkv;

  cvt_all<<<2048, 256, 0, stream>>>(x, w_qkv, w_out, xb, wqb, wob);

  gemm8p<0, 0><<<dim3(32, 12), 512, 0, stream>>>(xb, wqb, qkv, BATCH * T_SEQ, 3 * DM, DM);
  attn_kernel<<<512, 512, 0, stream>>>(qkv, att);
  gemm8p<1, 1><<<dim3(32, 8), 512, 0, stream>>>(att, wob, d_out, BATCH * T_SEQ, DM, DM);
}